// Round 5
// baseline (207.563 us; speedup 1.0000x reference)
//
#include <hip/hip_runtime.h>
#include <math.h>

// ClownSelector R14: token-per-lane + scalar-pipe proto (SGPR broadcast).
//
// R13 post-mortem: 43us, VALUBusy 36%, and 2->4 waves/SIMD bought only 10%
// => shared-pipe bound. DS arithmetic: 3x ds_read_b128 per kstep per wave
// (~36cyc) x 16 waves x 128 ksteps = ~74Kcyc + ~18Kcyc staging writes
// = ~38us DS occupancy vs 13.7us VALU. LDS-throughput-bound. Both k-loop
// reads are 8-way broadcast, but DS charges per-lane bytes (3KB/wave/kstep
// for 384 distinct B).
//
// R14: lane = token (wave covers 64 tokens), acc = all 64 experts per lane
// (float4 acc[16]). Per kstep: x = ONE ds_read_b32 (256B/wave, ~6cyc, 6x
// less DS) and proto[k][0..63] is WAVE-UNIFORM -> compiler emits
// s_load_dwordx4 into SGPRs (uniform addr, uniform control flow,
// __restrict__), feeding v_fmac_f32 vacc, s_proto, v_x. Proto traffic
// leaves the DS/L1 vector paths for the idle scalar pipe (L2-resident).
// Block: 1024 thr = 16 waves = 16-way k-split (64-wide), grid 256 = 1
// block/CU, 4 waves/SIMD. Tree: depth-4 pairwise, 2 buffers [64][76]
// (pad 76 -> 32 distinct start banks, 2-way free). k-order unchanged
// in family: ascending within slice + pairwise tree (R10/R13-proven).
// VGPR est ~95 (acc 64 + stage 16 + misc) < 128 cliff.

#define BB 8
#define SS 2048
#define DD 1024
#define EE 64
#define EPSV 1e-8f

#define SUMSQ4(v) ((v).x * (v).x + (v).y * (v).y + (v).z * (v).z + (v).w * (v).w)

// ---- K0: proto[e][d] -> ptt[d][e] -----------------------------------------
__global__ __launch_bounds__(256) void repack_proto(
    const float* __restrict__ proto, float* __restrict__ ptt) {
  const int gid = blockIdx.x * 256 + threadIdx.x;  // 0..65535
  const int d = gid >> 6;
  const int e = gid & 63;
  ptt[gid] = proto[(size_t)e * DD + d];
}

// ---- K1: normalized per-row dots ------------------------------------------
// SMEM layout (floats):
//   [    0 .. 16383]  xt: 16 waves x [16 k][64 tok]  (single-buffered)
//   [16384 .. 17407]  nq: 16 waves x [64 tok]
// Epilogue aliases B0 = SMEM[0..4863], B1 = SMEM[4864..9727] (dead xt).
__global__ __launch_bounds__(1024, 4) void router_dots(
    const float* __restrict__ x, const float* __restrict__ ptt,
    float* __restrict__ dots) {
  __shared__ float SMEM[17408];

  const int lane = threadIdx.x & 63;
  const int w    = __builtin_amdgcn_readfirstlane(threadIdx.x >> 6);  // 0..15
  const int b    = blockIdx.x >> 5;          // 32 blocks per batch
  const int s0   = (blockIdx.x & 31) * 64;   // 64 tokens per block

  const int toks = lane & 31;  // staging: token (A half; B half = +32)
  const int kh   = lane >> 5;  // staging: k-half (8 floats)

  float* xtw = SMEM + w * 1024;   // [16][64]
  float* nqp = SMEM + 16384;      // [16][64]

  const float* xb = x + ((size_t)b * SS + s0) * DD;
  const int kbase = w * 64;       // this wave's k-slice (64 wide)

  float4 acc[16];
#pragma unroll
  for (int i = 0; i < 16; ++i) acc[i] = make_float4(0.f, 0.f, 0.f, 0.f);
  float qA = 0.0f, qB = 0.0f;

  // ---- stage chunk 0: tokens 0..31 (A) and 32..63 (B), 16 k each ----
  {
    const float* xsA = xb + (size_t)toks * DD + kbase + kh * 8;
    const float* xsB = xsA + (size_t)32 * DD;
    const float4 a0 = *(const float4*)(xsA);
    const float4 a1 = *(const float4*)(xsA + 4);
    const float4 c0 = *(const float4*)(xsB);
    const float4 c1 = *(const float4*)(xsB + 4);
    qA += SUMSQ4(a0) + SUMSQ4(a1);
    qB += SUMSQ4(c0) + SUMSQ4(c1);
    float* d0 = xtw + toks;
    float* d1 = xtw + 32 + toks;
    d0[(kh * 8 + 0) * 64] = a0.x; d0[(kh * 8 + 1) * 64] = a0.y;
    d0[(kh * 8 + 2) * 64] = a0.z; d0[(kh * 8 + 3) * 64] = a0.w;
    d0[(kh * 8 + 4) * 64] = a1.x; d0[(kh * 8 + 5) * 64] = a1.y;
    d0[(kh * 8 + 6) * 64] = a1.z; d0[(kh * 8 + 7) * 64] = a1.w;
    d1[(kh * 8 + 0) * 64] = c0.x; d1[(kh * 8 + 1) * 64] = c0.y;
    d1[(kh * 8 + 2) * 64] = c0.z; d1[(kh * 8 + 3) * 64] = c0.w;
    d1[(kh * 8 + 4) * 64] = c1.x; d1[(kh * 8 + 5) * 64] = c1.y;
    d1[(kh * 8 + 6) * 64] = c1.z; d1[(kh * 8 + 7) * 64] = c1.w;
  }

  for (int c = 0; c < 4; ++c) {   // 4 chunks x 16 k = 64 k
    // ---- prefetch next chunk (consumed after the k-loop) ----
    float4 a0, a1, c0, c1;
    if (c + 1 < 4) {
      const float* xsA = xb + (size_t)toks * DD + kbase + (c + 1) * 16 + kh * 8;
      const float* xsB = xsA + (size_t)32 * DD;
      a0 = *(const float4*)(xsA);
      a1 = *(const float4*)(xsA + 4);
      c0 = *(const float4*)(xsB);
      c1 = *(const float4*)(xsB + 4);
    }
    // ---- 16 k-steps: 1 ds_read_b32 (x) + 16 uniform float4 loads (proto,
    //      scalarizes to s_load_dwordx4) + 64 v_fmac ----
    const float* pb = ptt + (size_t)(kbase + c * 16) * EE;
#pragma unroll
    for (int kk = 0; kk < 16; ++kk) {
      const float xk = xtw[kk * 64 + lane];
      const float4* pk = (const float4*)(pb + kk * EE);
#pragma unroll
      for (int i = 0; i < 16; ++i) {
        const float4 pv = pk[i];
        acc[i].x += xk * pv.x;
        acc[i].y += xk * pv.y;
        acc[i].z += xk * pv.z;
        acc[i].w += xk * pv.w;
      }
    }
    // ---- stage prefetched chunk (same buffer; wave-private DS in-order) ----
    if (c + 1 < 4) {
      qA += SUMSQ4(a0) + SUMSQ4(a1);
      qB += SUMSQ4(c0) + SUMSQ4(c1);
      float* d0 = xtw + toks;
      float* d1 = xtw + 32 + toks;
      d0[(kh * 8 + 0) * 64] = a0.x; d0[(kh * 8 + 1) * 64] = a0.y;
      d0[(kh * 8 + 2) * 64] = a0.z; d0[(kh * 8 + 3) * 64] = a0.w;
      d0[(kh * 8 + 4) * 64] = a1.x; d0[(kh * 8 + 5) * 64] = a1.y;
      d0[(kh * 8 + 6) * 64] = a1.z; d0[(kh * 8 + 7) * 64] = a1.w;
      d1[(kh * 8 + 0) * 64] = c0.x; d1[(kh * 8 + 1) * 64] = c0.y;
      d1[(kh * 8 + 2) * 64] = c0.z; d1[(kh * 8 + 3) * 64] = c0.w;
      d1[(kh * 8 + 4) * 64] = c1.x; d1[(kh * 8 + 5) * 64] = c1.y;
      d1[(kh * 8 + 6) * 64] = c1.z; d1[(kh * 8 + 7) * 64] = c1.w;
    }
  }

  // sumsq: combine the two k-halves; kh==0 lanes publish both token groups
  qA += __shfl_xor(qA, 32);
  qB += __shfl_xor(qB, 32);
  if (kh == 0) {
    nqp[w * 64 + toks]      = qA;
    nqp[w * 64 + 32 + toks] = qB;
  }

  // epilogue reduction buffers alias the (now dead) xt region
  float* B0 = SMEM;          // [64][76]
  float* B1 = SMEM + 4864;   // [64][76]

#define WRB(R)                                                       \
  { _Pragma("unroll") for (int i = 0; i < 16; ++i)                   \
      *(float4*)((R) + lane * 76 + i * 4) = acc[i]; }
#define ADDB(R)                                                      \
  { _Pragma("unroll") for (int i = 0; i < 16; ++i) {                 \
      const float4 t = *(const float4*)((R) + lane * 76 + i * 4);    \
      acc[i].x += t.x; acc[i].y += t.y;                              \
      acc[i].z += t.z; acc[i].w += t.w; } }

  // deterministic pairwise tree over 16 waves, 2 buffers
  // D1: (0,1)(4,5) | (2,3)(6,7) | (8,9)(12,13) | (10,11)(14,15)
  __syncthreads();
  if (w == 1) WRB(B0)  if (w == 5) WRB(B1)
  __syncthreads();
  if (w == 0) ADDB(B0) if (w == 4) ADDB(B1)
  __syncthreads();
  if (w == 3) WRB(B0)  if (w == 7) WRB(B1)
  __syncthreads();
  if (w == 2) ADDB(B0) if (w == 6) ADDB(B1)
  __syncthreads();
  if (w == 9) WRB(B0)  if (w == 13) WRB(B1)
  __syncthreads();
  if (w == 8) ADDB(B0) if (w == 12) ADDB(B1)
  __syncthreads();
  if (w == 11) WRB(B0) if (w == 15) WRB(B1)
  __syncthreads();
  if (w == 10) ADDB(B0) if (w == 14) ADDB(B1)
  // D2: (0,2)(4,6) | (8,10)(12,14)
  __syncthreads();
  if (w == 2) WRB(B0)  if (w == 6) WRB(B1)
  __syncthreads();
  if (w == 0) ADDB(B0) if (w == 4) ADDB(B1)
  __syncthreads();
  if (w == 10) WRB(B0) if (w == 14) WRB(B1)
  __syncthreads();
  if (w == 8) ADDB(B0) if (w == 12) ADDB(B1)
  // D3: (0,4)(8,12)
  __syncthreads();
  if (w == 4) WRB(B0)  if (w == 12) WRB(B1)
  __syncthreads();
  if (w == 0) ADDB(B0) if (w == 8) ADDB(B1)
  // D4: (0,8)
  __syncthreads();
  if (w == 8) WRB(B0)
  __syncthreads();
  if (w == 0) {
    ADDB(B0)
    float qs = 0.0f;
#pragma unroll
    for (int i = 0; i < 16; ++i) qs += nqp[i * 64 + lane];
    const float inv = 1.0f / fmaxf(sqrtf(qs), EPSV);
    float* dp = dots + ((size_t)b * SS + s0 + lane) * EE;
#pragma unroll
    for (int i = 0; i < 16; ++i) {
      float4 o = acc[i];
      o.x *= inv; o.y *= inv; o.z *= inv; o.w *= inv;
      *(float4*)(dp + i * 4) = o;
    }
  }
}

// ---- K2: window-3 + top-2 + renorm softmax (array-free, R7-verified) -------
#define T2UP(s, ei)                                            \
  if ((s) > v1) { v2 = v1; i2 = i1; v1 = (s); i1 = (ei); }     \
  else if ((s) > v2) { v2 = (s); i2 = (ei); }

__global__ __launch_bounds__(256) void router_top2(
    const float* __restrict__ dots, float* __restrict__ out) {
  const int gtid = blockIdx.x * 256 + threadIdx.x;  // 0..32767
  const int tok  = gtid >> 1;          // global token
  const int h    = gtid & 1;           // expert half (32 each)
  const int b    = tok >> 11;
  const int sl   = tok & (SS - 1);
  const int r0   = (sl >= 2) ? sl - 2 : 0;   // causal pad: replicate token 0
  const int r1   = (sl >= 1) ? sl - 1 : 0;

  const float* d0 = dots + ((size_t)b * SS + r0) * EE + h * 32;
  const float* d1 = dots + ((size_t)b * SS + r1) * EE + h * 32;
  const float* d2 = dots + ((size_t)b * SS + sl) * EE + h * 32;

  float v1 = -INFINITY, v2 = -INFINITY;
  int i1 = 0, i2 = 0;
#pragma unroll
  for (int qd = 0; qd < 8; ++qd) {
    const float4 a = *(const float4*)(d0 + qd * 4);
    const float4 c = *(const float4*)(d1 + qd * 4);
    const float4 e = *(const float4*)(d2 + qd * 4);
    const int e0 = h * 32 + qd * 4;
    float s;
    s = a.x + c.x + e.x; T2UP(s, e0 + 0)
    s = a.y + c.y + e.y; T2UP(s, e0 + 1)
    s = a.z + c.z + e.z; T2UP(s, e0 + 2)
    s = a.w + c.w + e.w; T2UP(s, e0 + 3)
  }

  {  // merge the two halves (partner lane = lane^1); tie -> lower index
    const float ov1 = __shfl_xor(v1, 1);
    const int   oi1 = __shfl_xor(i1, 1);
    const float ov2 = __shfl_xor(v2, 1);
    const int   oi2 = __shfl_xor(i2, 1);
    const bool o_beats = (ov1 > v1) || (ov1 == v1 && oi1 < i1);
    if (o_beats) {
      const bool v1_beats_o2 = (v1 > ov2) || (v1 == ov2 && i1 < oi2);
      v2 = v1_beats_o2 ? v1 : ov2;
      i2 = v1_beats_o2 ? i1 : oi2;
      v1 = ov1;
      i1 = oi1;
    } else {
      const bool o1_beats_v2 = (ov1 > v2) || (ov1 == v2 && oi1 < i2);
      if (o1_beats_v2) { v2 = ov1; i2 = oi1; }
    }
  }

  if (h == 0) {
    const float ex = expf((v2 - v1) * (1.0f / 3.0f));  // <= 1
    const float w1 = 1.0f / (1.0f + ex);
    const size_t o = (size_t)tok * 2;
    *(float2*)(out + o) = make_float2((float)i1, (float)i2);
    *(float2*)(out + (size_t)BB * SS * 2 + o) = make_float2(w1, ex * w1);
  }
}

extern "C" void kernel_launch(void* const* d_in, const int* in_sizes, int n_in,
                              void* d_out, int out_size, void* d_ws, size_t ws_size,
                              hipStream_t stream) {
  const float* x     = (const float*)d_in[0];
  const float* proto = (const float*)d_in[1];
  // d_in[2] = attn_mask: unused by the reference output path.
  float* out  = (float*)d_out;
  float* ptt  = (float*)d_ws;                          // 256 KiB ptt[d][e]
  float* dots = (float*)((char*)d_ws + (512 << 10));   // 4 MiB normalized dots

  repack_proto<<<dim3(256), dim3(256), 0, stream>>>(proto, ptt);
  router_dots<<<dim3(256), dim3(1024), 0, stream>>>(x, ptt, dots);
  router_top2<<<dim3(128), dim3(256), 0, stream>>>(dots, out);
}

// Round 6
// 132.543 us; speedup vs baseline: 1.5660x; 1.5660x over previous
//
#include <hip/hip_runtime.h>
#include <math.h>

// ClownSelector R15: scalar-pipe proto (SGPR) + tiny acc + minimal LDS x.
//
// R14 post-mortem: compiler capped VGPR at 64 for the 1024-thr block; the
// 64-float acc spilled (WRITE 4->41MB, FETCH 34->74GB => 127us). But
// SGPR=112 & LDS-conflict=0 suggest the proto scalarization DID fire.
// => keep the mechanism, shrink the acc 4x so it fits ANY plausible cap.
//
// R15 decomposition (block = 1024 thr = 16 waves, grid 256, lane = token):
//   wave w: we=w&3 -> experts [we*16,+16)  => acc = 4 float4 (16 VGPR)
//           wk=w>>2 -> K quarter [wk*256,+256)
//   per kstep: xk = 1 conflict-free ds_read_b32 (x staged [k][tok] per
//   group, coalesced 64B-segment global loads, dbuf, 1 barrier/chunk);
//   proto[k][we*16..+16) is wave-uniform via __restrict__ const ptr in
//   uniform control flow -> s_load_dwordx16 -> v_fmac_f32 v,s,v (1 SGPR
//   per VALU instr: legal). sumsq folds in at use (q += xk*xk).
// Pipes/CU: VALU ~35Kcyc (14.5us floor), DS ~12Kcyc, SMEM 64B/kstep/wave.
// Regs ~45 VGPR -> spill-proof even at a 64 cap. Epilogue: depth-2 tree
// over wk in LDS planes [we][quad][64 tok][4] (optimal 8-phase b128),
// aliasing the dead x region. LDS ~33KB.

#define BB 8
#define SS 2048
#define DD 1024
#define EE 64
#define EPSV 1e-8f

// ---- K0: proto[e][d] -> ptt[d][e] -----------------------------------------
__global__ __launch_bounds__(256) void repack_proto(
    const float* __restrict__ proto, float* __restrict__ ptt) {
  const int gid = blockIdx.x * 256 + threadIdx.x;  // 0..65535
  const int d = gid >> 6;
  const int e = gid & 63;
  ptt[gid] = proto[(size_t)e * DD + d];
}

// ---- K1: normalized per-row dots ------------------------------------------
// SMEM layout (floats):
//   [   0 .. 8191]  xt: 4 wk-groups x [2 buf][16 k][64 tok]
//   [8192 .. 8447]  nq: [4 wk][64 tok]
// Epilogue aliases B0 = SMEM[0..4095], B1 = SMEM[4096..8191] (dead xt),
// each laid out [4 we][4 quad][64 tok][4 floats].
__global__ __launch_bounds__(1024) void router_dots(
    const float* __restrict__ x, const float* __restrict__ ptt,
    float* __restrict__ dots) {
  __shared__ float SMEM[8448];

  const int tid  = threadIdx.x;
  const int lane = tid & 63;
  const int w    = __builtin_amdgcn_readfirstlane(tid >> 6);  // 0..15
  const int we   = w & 3;    // expert quad-group: experts [we*16, +16)
  const int wk   = w >> 2;   // K quarter: [wk*256, +256)
  const int b    = blockIdx.x >> 5;          // 8 batches
  const int s0   = (blockIdx.x & 31) * 64;   // 64 tokens per block

  // staging role within the wk-group (4 waves = 256 lanes):
  const int gl = tid & 255;
  const int st = gl >> 2;    // staging token 0..63
  const int sq = gl & 3;     // staging k-quad 0..3 (4 consecutive k)

  float* xtw = SMEM + wk * 2048;   // [2][16][64]
  float* nqp = SMEM + 8192;        // [4][64]

  // lane-coalesced global source: 4 consecutive k of token st
  const float* xsrow =
      x + ((size_t)b * SS + s0 + st) * DD + wk * 256 + sq * 4;
  // wave-uniform proto slice base
  const float* pr = ptt + (size_t)(wk * 256) * EE + we * 16;

  float4 acc0 = make_float4(0.f, 0.f, 0.f, 0.f);
  float4 acc1 = make_float4(0.f, 0.f, 0.f, 0.f);
  float4 acc2 = make_float4(0.f, 0.f, 0.f, 0.f);
  float4 acc3 = make_float4(0.f, 0.f, 0.f, 0.f);
  float q = 0.0f;

  // ---- prologue: stage chunk 0 into buf 0 (transpose [k][tok]) ----
  {
    const float4 v = *(const float4*)(xsrow);
    float* d = xtw + (sq * 4) * 64 + st;
    d[0]   = v.x;
    d[64]  = v.y;
    d[128] = v.z;
    d[192] = v.w;
  }
  __syncthreads();

  for (int c = 0; c < 16; ++c) {   // 16 chunks x 16 k = 256 k per wave
    const int buf = c & 1;
    // ---- issue next chunk's global load early (latency hides under fmacs) --
    float4 nv;
    if (c + 1 < 16) nv = *(const float4*)(xsrow + (c + 1) * 16);
    // ---- 16 k-steps: 1 ds_read_b32 + s_load'd proto + 16 fmac + 1 sumsq ----
    const float* xk_base = xtw + buf * 1024 + lane;
    const float* pp = pr + (size_t)(c * 16) * EE;
#pragma unroll
    for (int kk = 0; kk < 16; ++kk) {
      const float xk = xk_base[kk * 64];
      q += xk * xk;
      const float4 p0 = *(const float4*)(pp + kk * 64);
      const float4 p1 = *(const float4*)(pp + kk * 64 + 4);
      const float4 p2 = *(const float4*)(pp + kk * 64 + 8);
      const float4 p3 = *(const float4*)(pp + kk * 64 + 12);
      acc0.x += xk * p0.x; acc0.y += xk * p0.y;
      acc0.z += xk * p0.z; acc0.w += xk * p0.w;
      acc1.x += xk * p1.x; acc1.y += xk * p1.y;
      acc1.z += xk * p1.z; acc1.w += xk * p1.w;
      acc2.x += xk * p2.x; acc2.y += xk * p2.y;
      acc2.z += xk * p2.z; acc2.w += xk * p2.w;
      acc3.x += xk * p3.x; acc3.y += xk * p3.y;
      acc3.z += xk * p3.z; acc3.w += xk * p3.w;
    }
    // ---- write staged chunk into the other buffer ----
    if (c + 1 < 16) {
      float* d = xtw + (buf ^ 1) * 1024 + (sq * 4) * 64 + st;
      d[0]   = nv.x;
      d[64]  = nv.y;
      d[128] = nv.z;
      d[192] = nv.w;
    }
    __syncthreads();
  }

  // per-token sumsq partial for this K quarter (identical across we-waves)
  if (we == 0) nqp[wk * 64 + lane] = q;

  // epilogue tree buffers alias the (now dead) xt region.
  // plane layout: base + we*1024 + quad*256 + lane*4  (8-phase-optimal b128)
  float* B0 = SMEM;
  float* B1 = SMEM + 4096;

#define WRB(R)                                              \
  { float* p_ = (R) + we * 1024 + lane * 4;                 \
    *(float4*)(p_ + 0)   = acc0;                            \
    *(float4*)(p_ + 256) = acc1;                            \
    *(float4*)(p_ + 512) = acc2;                            \
    *(float4*)(p_ + 768) = acc3; }
#define ADDB(R)                                             \
  { const float* p_ = (R) + we * 1024 + lane * 4;           \
    const float4 t0 = *(const float4*)(p_ + 0);             \
    const float4 t1 = *(const float4*)(p_ + 256);           \
    const float4 t2 = *(const float4*)(p_ + 512);           \
    const float4 t3 = *(const float4*)(p_ + 768);           \
    acc0.x += t0.x; acc0.y += t0.y; acc0.z += t0.z; acc0.w += t0.w; \
    acc1.x += t1.x; acc1.y += t1.y; acc1.z += t1.z; acc1.w += t1.w; \
    acc2.x += t2.x; acc2.y += t2.y; acc2.z += t2.z; acc2.w += t2.w; \
    acc3.x += t3.x; acc3.y += t3.y; acc3.z += t3.z; acc3.w += t3.w; }

  // deterministic tree over wk: (0+1) + (2+3)
  __syncthreads();
  if (wk == 1) WRB(B0)
  if (wk == 3) WRB(B1)
  __syncthreads();
  if (wk == 0) ADDB(B0)
  if (wk == 2) ADDB(B1)
  __syncthreads();
  if (wk == 2) WRB(B0)
  __syncthreads();
  if (wk == 0) {
    ADDB(B0)
    const float qs = nqp[lane] + nqp[64 + lane] +
                     nqp[128 + lane] + nqp[192 + lane];
    const float inv = 1.0f / fmaxf(sqrtf(qs), EPSV);
    acc0.x *= inv; acc0.y *= inv; acc0.z *= inv; acc0.w *= inv;
    acc1.x *= inv; acc1.y *= inv; acc1.z *= inv; acc1.w *= inv;
    acc2.x *= inv; acc2.y *= inv; acc2.z *= inv; acc2.w *= inv;
    acc3.x *= inv; acc3.y *= inv; acc3.z *= inv; acc3.w *= inv;
    float* dp = dots + ((size_t)b * SS + s0 + lane) * EE + we * 16;
    *(float4*)(dp)      = acc0;
    *(float4*)(dp + 4)  = acc1;
    *(float4*)(dp + 8)  = acc2;
    *(float4*)(dp + 12) = acc3;
  }
}

// ---- K2: window-3 + top-2 + renorm softmax (array-free, R7-verified) -------
#define T2UP(s, ei)                                            \
  if ((s) > v1) { v2 = v1; i2 = i1; v1 = (s); i1 = (ei); }     \
  else if ((s) > v2) { v2 = (s); i2 = (ei); }

__global__ __launch_bounds__(256) void router_top2(
    const float* __restrict__ dots, float* __restrict__ out) {
  const int gtid = blockIdx.x * 256 + threadIdx.x;  // 0..32767
  const int tok  = gtid >> 1;          // global token
  const int h    = gtid & 1;           // expert half (32 each)
  const int b    = tok >> 11;
  const int sl   = tok & (SS - 1);
  const int r0   = (sl >= 2) ? sl - 2 : 0;   // causal pad: replicate token 0
  const int r1   = (sl >= 1) ? sl - 1 : 0;

  const float* d0 = dots + ((size_t)b * SS + r0) * EE + h * 32;
  const float* d1 = dots + ((size_t)b * SS + r1) * EE + h * 32;
  const float* d2 = dots + ((size_t)b * SS + sl) * EE + h * 32;

  float v1 = -INFINITY, v2 = -INFINITY;
  int i1 = 0, i2 = 0;
#pragma unroll
  for (int qd = 0; qd < 8; ++qd) {
    const float4 a = *(const float4*)(d0 + qd * 4);
    const float4 c = *(const float4*)(d1 + qd * 4);
    const float4 e = *(const float4*)(d2 + qd * 4);
    const int e0 = h * 32 + qd * 4;
    float s;
    s = a.x + c.x + e.x; T2UP(s, e0 + 0)
    s = a.y + c.y + e.y; T2UP(s, e0 + 1)
    s = a.z + c.z + e.z; T2UP(s, e0 + 2)
    s = a.w + c.w + e.w; T2UP(s, e0 + 3)
  }

  {  // merge the two halves (partner lane = lane^1); tie -> lower index
    const float ov1 = __shfl_xor(v1, 1);
    const int   oi1 = __shfl_xor(i1, 1);
    const float ov2 = __shfl_xor(v2, 1);
    const int   oi2 = __shfl_xor(i2, 1);
    const bool o_beats = (ov1 > v1) || (ov1 == v1 && oi1 < i1);
    if (o_beats) {
      const bool v1_beats_o2 = (v1 > ov2) || (v1 == ov2 && i1 < oi2);
      v2 = v1_beats_o2 ? v1 : ov2;
      i2 = v1_beats_o2 ? i1 : oi2;
      v1 = ov1;
      i1 = oi1;
    } else {
      const bool o1_beats_v2 = (ov1 > v2) || (ov1 == v2 && oi1 < i2);
      if (o1_beats_v2) { v2 = ov1; i2 = oi1; }
    }
  }

  if (h == 0) {
    const float ex = expf((v2 - v1) * (1.0f / 3.0f));  // <= 1
    const float w1 = 1.0f / (1.0f + ex);
    const size_t o = (size_t)tok * 2;
    *(float2*)(out + o) = make_float2((float)i1, (float)i2);
    *(float2*)(out + (size_t)BB * SS * 2 + o) = make_float2(w1, ex * w1);
  }
}

extern "C" void kernel_launch(void* const* d_in, const int* in_sizes, int n_in,
                              void* d_out, int out_size, void* d_ws, size_t ws_size,
                              hipStream_t stream) {
  const float* x     = (const float*)d_in[0];
  const float* proto = (const float*)d_in[1];
  // d_in[2] = attn_mask: unused by the reference output path.
  float* out  = (float*)d_out;
  float* ptt  = (float*)d_ws;                          // 256 KiB ptt[d][e]
  float* dots = (float*)((char*)d_ws + (512 << 10));   // 4 MiB normalized dots

  repack_proto<<<dim3(256), dim3(256), 0, stream>>>(proto, ptt);
  router_dots<<<dim3(256), dim3(1024), 0, stream>>>(x, ptt, dots);
  router_top2<<<dim3(128), dim3(256), 0, stream>>>(dots, out);
}